// Round 11
// baseline (148.082 us; speedup 1.0000x reference)
//
#include <hip/hip_runtime.h>
#include <hip/hip_bf16.h>

// N=4, S=2048, D_MODEL=1024, HEADS=16, HEAD_DIM=64. M = 8192 tokens, E = 3072.

typedef __hip_bfloat16 bf16;
using bf16x8 = __attribute__((ext_vector_type(8))) short;
using f32x4  = __attribute__((ext_vector_type(4))) float;

__device__ __forceinline__ float b2f(unsigned short u) {
    return __uint_as_float(((unsigned)u) << 16);
}
__device__ __forceinline__ unsigned short f2b(float f) {
    bf16 h = __float2bfloat16(f);
    return *reinterpret_cast<unsigned short*>(&h);
}
__device__ __forceinline__ void store1(float* p, float v) { *p = v; }
__device__ __forceinline__ void store1(bf16* p, float v) { *p = __float2bfloat16(v); }

// async global->LDS, 16B per lane. LDS dest = wave-uniform base + lane*16.
__device__ __forceinline__ void gload_lds16(const bf16* g, bf16* l) {
    __builtin_amdgcn_global_load_lds(
        (const __attribute__((address_space(1))) void*)g,
        (__attribute__((address_space(3))) void*)l, 16, 0, 0);
}

#define BAR()   __builtin_amdgcn_s_barrier()
#define LGKM(N) asm volatile("s_waitcnt lgkmcnt(" #N ")" ::: "memory")
#define VMC(N)  asm volatile("s_waitcnt vmcnt(" #N ")" ::: "memory")

// ============================================================================
// Min-sync pipelined GEMM (r10 structure) + optional fused fp32->bf16 A-path.
// C = A*B^T + bias. Tile 128(M) x 256(N), BK=64, 512 thr = 8 waves (2Mx4N),
// wave out 64x64 = acc[4][4]. LDS 144KB = 3 bufs -> 1 block/CU.
// Swizzle (verified r7-r10, 0 conflicts): read byte ^= (row&7)<<4.
//   B: inverse on GLOBAL k (kel), linear gload_lds dest.
//   A (AFP32): swizzle applied at ds_write (both-sides rule, reg-staged).
// AFP32 per-tile: { 16 frag reads; stage B(t+2) 4 gload_lds;
//   VMC(4) [queue B(t+1),Areg(t+2),B(t+2) -> completes B(t+1)+Areg(t+2)];
//   cvt+2 ds_write A(t+2); issue Areg(t+3) 4 dwordx4;
//   LGKM(8) MFMA kk0; LGKM(2) MFMA kk1; LGKM(0); BAR }
// Tails (t+2>=nt): VMC(0), no writes, LGKM(0) variants.
// !AFP32: r10 schedule verbatim (gload_lds A, VMC(6)/VMC(0) at end).
// Hazard: A-write/B-stage target buf (t-1)%3; its reads retired before
// BAR(t-1) (LGKM before MFMA kk1) -> BAR orders write-after-read.
// ============================================================================
template <bool AFP32, typename CT>
__global__ __launch_bounds__(512, 2)
void gemmf(const void* __restrict__ Av, const bf16* __restrict__ B,
           const float* __restrict__ bias, CT* __restrict__ C,
           int M, int N, int K, int gx) {
    __shared__ alignas(1024) bf16 smem[3][384 * 64];  // per buf: A[0:8192) B[8192:24576)

    const int t    = threadIdx.x;
    const int lane = t & 63;
    const int wid  = t >> 6;
    const int wr   = wid >> 2;
    const int wc   = wid & 3;

    // XCD-aware bijective remap (gridDim.x % 8 == 0)
    const int nwg = gridDim.x;
    const int bid = blockIdx.x;
    const int wg  = (bid & 7) * (nwg >> 3) + (bid >> 3);
    const int m0  = (wg / gx) * 128;
    const int n0  = (wg % gx) * 256;
    const int nt  = K / 64;

    const int srow = lane >> 3;
    const int kel  = ((lane & 7) ^ (lane >> 3)) * 8;   // inverse swizzle (B path)

    auto stageB = [&](int tt, int h) {
        if (tt >= nt) return;
        bf16* lp = &smem[tt % 3][8192 + h * 8192 + wid * 1024];
        const bf16* gp = B + (size_t)(n0 + h * 128 + wid * 16 + srow) * K + tt * 64 + kel;
        gload_lds16(gp, lp);
        gload_lds16(gp + (size_t)8 * K, lp + 512);
    };
    auto stageA16 = [&](int tt) {          // !AFP32: bf16 A via gload_lds
        if (tt >= nt) return;
        const bf16* A = (const bf16*)Av;
        bf16* lp = &smem[tt % 3][wid * 1024];
        const bf16* gp = A + (size_t)(m0 + wid * 16 + srow) * K + tt * 64 + kel;
        gload_lds16(gp, lp);
        gload_lds16(gp + (size_t)8 * K, lp + 512);
    };

    // AFP32 A-path: thread t stages row arow, 16 elems at logical bytes akb0..+31
    const int arow = t >> 2;               // 0..127
    const int akb0 = (t & 3) * 32;         // logical byte offset in 128B row
    float4 ar0, ar1, ar2, ar3;             // in-flight fp32 A data (tile t+2/t+3)
    auto aregLoad = [&](int tt) {
        if (tt >= nt) return;
        const float* A = (const float*)Av;
        const float* gp = A + (size_t)(m0 + arow) * K + tt * 64 + (akb0 >> 1);
        ar0 = ((const float4*)gp)[0];
        ar1 = ((const float4*)gp)[1];
        ar2 = ((const float4*)gp)[2];
        ar3 = ((const float4*)gp)[3];
    };
    auto aWriteF = [&](int tt, float4 f0, float4 f1, float4 f2, float4 f3) {
        char* base = (char*)&smem[tt % 3][0];
        const int swz = (arow & 7) << 4;
        uint4 w0, w1;
        w0.x = (unsigned)f2b(f0.x) | ((unsigned)f2b(f0.y) << 16);
        w0.y = (unsigned)f2b(f0.z) | ((unsigned)f2b(f0.w) << 16);
        w0.z = (unsigned)f2b(f1.x) | ((unsigned)f2b(f1.y) << 16);
        w0.w = (unsigned)f2b(f1.z) | ((unsigned)f2b(f1.w) << 16);
        w1.x = (unsigned)f2b(f2.x) | ((unsigned)f2b(f2.y) << 16);
        w1.y = (unsigned)f2b(f2.z) | ((unsigned)f2b(f2.w) << 16);
        w1.z = (unsigned)f2b(f3.x) | ((unsigned)f2b(f3.y) << 16);
        w1.w = (unsigned)f2b(f3.z) | ((unsigned)f2b(f3.w) << 16);
        *(uint4*)(base + arow * 128 + (akb0 ^ swz))        = w0;
        *(uint4*)(base + arow * 128 + ((akb0 + 16) ^ swz)) = w1;
    };

    // swizzled ds_read of one 16x16x32 fragment
    const int arow_base = wr * 64 + (lane & 15);
    const int brow_base = wc * 64 + (lane & 15);
    const int kqb       = (lane >> 4) * 16;
    auto LDA = [&](int buf, int kk, int m) -> bf16x8 {
        const int row = arow_base + m * 16;
        const int ab  = row * 128 + ((kk * 64 + kqb) ^ ((row & 7) << 4));
        return *(const bf16x8*)((const char*)&smem[buf][0] + ab);
    };
    auto LDB = [&](int buf, int kk, int n) -> bf16x8 {
        const int row = brow_base + n * 16;
        const int bb  = 16384 + row * 128 + ((kk * 64 + kqb) ^ ((row & 7) << 4));
        return *(const bf16x8*)((const char*)&smem[buf][0] + bb);
    };

    f32x4 acc[4][4] = {};
    bf16x8 af0[4], bv0[4], af1[4], bv1[4];

    // ---- prologue ----
    if constexpr (AFP32) {
        stageB(0, 0); stageB(0, 1); stageB(1, 0); stageB(1, 1);
        const float* A = (const float*)Av;
        const float* g0 = A + (size_t)(m0 + arow) * K + (akb0 >> 1);
        const float* g1 = g0 + 64;
        float4 p0 = ((const float4*)g0)[0], p1 = ((const float4*)g0)[1],
               p2 = ((const float4*)g0)[2], p3 = ((const float4*)g0)[3];
        float4 q0 = ((const float4*)g1)[0], q1 = ((const float4*)g1)[1],
               q2 = ((const float4*)g1)[2], q3 = ((const float4*)g1)[3];
        VMC(0);
        aWriteF(0, p0, p1, p2, p3);
        aWriteF(1, q0, q1, q2, q3);
        aregLoad(2);
        LGKM(0);
        BAR();
    } else {
        stageA16(0); stageB(0, 0); stageB(0, 1);
        stageA16(1); stageB(1, 0); stageB(1, 1);
        VMC(6);
        BAR();
    }

    for (int tt = 0; tt < nt; ++tt) {
        const int buf = tt % 3;

        // 16 frag reads: kk0 (oldest 8), then kk1
#pragma unroll
        for (int m = 0; m < 4; ++m) af0[m] = LDA(buf, 0, m);
#pragma unroll
        for (int n = 0; n < 4; ++n) bv0[n] = LDB(buf, 0, n);
#pragma unroll
        for (int m = 0; m < 4; ++m) af1[m] = LDA(buf, 1, m);
#pragma unroll
        for (int n = 0; n < 4; ++n) bv1[n] = LDB(buf, 1, n);
        // stage B(t+2)
        stageB(tt + 2, 0); stageB(tt + 2, 1);
        // A path
        if constexpr (AFP32) {
            if (tt + 2 < nt) {
                VMC(4);                  // completes B(t+1) and Areg(t+2)
                aWriteF(tt + 2, ar0, ar1, ar2, ar3);
                aregLoad(tt + 3);
            } else {
                VMC(0);
            }
        } else {
            stageA16(tt + 2);
        }

        LGKM(8);                         // kk0 frags ready
        __builtin_amdgcn_s_setprio(1);
#pragma unroll
        for (int m = 0; m < 4; ++m)
#pragma unroll
            for (int n = 0; n < 4; ++n)
                acc[m][n] = __builtin_amdgcn_mfma_f32_16x16x32_bf16(
                    af0[m], bv0[n], acc[m][n], 0, 0, 0);
        __builtin_amdgcn_s_setprio(0);
        if constexpr (AFP32) {
            if (tt + 2 < nt) { LGKM(2); } else { LGKM(0); }
        } else {
            LGKM(0);
        }
        __builtin_amdgcn_s_setprio(1);
#pragma unroll
        for (int m = 0; m < 4; ++m)
#pragma unroll
            for (int n = 0; n < 4; ++n)
                acc[m][n] = __builtin_amdgcn_mfma_f32_16x16x32_bf16(
                    af1[m], bv1[n], acc[m][n], 0, 0, 0);
        __builtin_amdgcn_s_setprio(0);

        if constexpr (AFP32) {
            LGKM(0);                     // A-writes visible before BAR
        } else {
            if (tt < nt - 2) { VMC(6); } else { VMC(0); }
        }
        BAR();
    }

    // epilogue
#pragma unroll
    for (int m = 0; m < 4; ++m) {
        const int row = m0 + wr * 64 + m * 16 + (lane >> 4) * 4;
#pragma unroll
        for (int n = 0; n < 4; ++n) {
            const int col = n0 + wc * 64 + n * 16 + (lane & 15);
            const float bval = bias[col];
#pragma unroll
            for (int r = 0; r < 4; ++r)
                store1(&C[(size_t)(row + r) * N + col], acc[m][n][r] + bval);
        }
    }
}

// ---- fp32 -> bf16 conversion, 4 elems/thread ----
__global__ __launch_bounds__(256)
void cvt_f32_bf16(const float* __restrict__ in, bf16* __restrict__ out, int n4) {
    int i = blockIdx.x * 256 + threadIdx.x;
    if (i >= n4) return;
    float4 v = ((const float4*)in)[i];
    ushort4 o = {f2b(v.x), f2b(v.y), f2b(v.z), f2b(v.w)};
    ((ushort4*)out)[i] = o;
}

// ---- Per-token attention over heads axis + scrambled T write ----
__global__ __launch_bounds__(256)
void attn_kernel(const bf16* __restrict__ qkv, bf16* __restrict__ T) {
    __shared__ float lds[4][48 * 68];

    const int wave = threadIdx.x >> 6;
    const int lane = threadIdx.x & 63;
    const int token = blockIdx.x * 4 + wave;
    const int n = token >> 11;
    const int s = token & 2047;

    float* L = lds[wave];
    const bf16* src = qkv + (size_t)token * 3072;

#pragma unroll
    for (int i = 0; i < 6; ++i) {
        int idx = i * 64 + lane;
        uint4 v = *reinterpret_cast<const uint4*>(src + (size_t)idx * 8);
        int e0 = idx * 8;
        float* dst = &L[(e0 >> 6) * 68 + (e0 & 63)];
        float4 a, b;
        a.x = b2f((unsigned short)(v.x & 0xffff));
        a.y = b2f((unsigned short)(v.x >> 16));
        a.z = b2f((unsigned short)(v.y & 0xffff));
        a.w = b2f((unsigned short)(v.y >> 16));
        b.x = b2f((unsigned short)(v.z & 0xffff));
        b.y = b2f((unsigned short)(v.z >> 16));
        b.z = b2f((unsigned short)(v.w & 0xffff));
        b.w = b2f((unsigned short)(v.w >> 16));
        *(float4*)dst = a;
        *(float4*)(dst + 4) = b;
    }
    __syncthreads();

    const int q0 = lane & 15;
    const int g  = lane >> 4;

    float e[4] = {0.f, 0.f, 0.f, 0.f};
    const float* Qr = &L[q0 * 68];
    const float* K0 = &L[(16 + g * 4) * 68];
#pragma unroll
    for (int d = 0; d < 64; d += 4) {
        float4 q4 = *(const float4*)(Qr + d);
#pragma unroll
        for (int j = 0; j < 4; ++j) {
            float4 k4 = *(const float4*)(K0 + j * 68 + d);
            e[j] += q4.x * k4.x + q4.y * k4.y + q4.z * k4.z + q4.w * k4.w;
        }
    }
#pragma unroll
    for (int j = 0; j < 4; ++j) e[j] *= 0.125f;

    float m = fmaxf(fmaxf(e[0], e[1]), fmaxf(e[2], e[3]));
    m = fmaxf(m, __shfl_xor(m, 16));
    m = fmaxf(m, __shfl_xor(m, 32));
    float p[4], sum = 0.f;
#pragma unroll
    for (int j = 0; j < 4; ++j) { p[j] = __expf(e[j] - m); sum += p[j]; }
    sum += __shfl_xor(sum, 16);
    sum += __shfl_xor(sum, 32);
    const float inv = 1.0f / sum;

    float prow[16];
#pragma unroll
    for (int j = 0; j < 4; ++j) {
        prow[g * 4 + j]         = p[j] * inv;
        prow[((g ^ 1) * 4) + j] = __shfl_xor(p[j], 16) * inv;
        prow[((g ^ 2) * 4) + j] = __shfl_xor(p[j], 32) * inv;
        prow[((g ^ 3) * 4) + j] = __shfl_xor(p[j], 48) * inv;
    }

    const int d0 = g * 16;
    float4 o4[4] = {};
#pragma unroll
    for (int k = 0; k < 16; ++k) {
        const float p1 = prow[k];
        const float* Vr = &L[(32 + k) * 68 + d0];
#pragma unroll
        for (int c = 0; c < 4; ++c) {
            float4 v = *(const float4*)(Vr + c * 4);
            o4[c].x += p1 * v.x; o4[c].y += p1 * v.y;
            o4[c].z += p1 * v.z; o4[c].w += p1 * v.w;
        }
    }
    unsigned short outv[16];
#pragma unroll
    for (int c = 0; c < 4; ++c) {
        outv[c * 4 + 0] = f2b(o4[c].x); outv[c * 4 + 1] = f2b(o4[c].y);
        outv[c * 4 + 2] = f2b(o4[c].z); outv[c * 4 + 3] = f2b(o4[c].w);
    }
    const int sp = q0 * 128 + (s >> 4);
    size_t off = ((size_t)n * 2048 + sp) * 1024 + (size_t)(s & 15) * 64 + d0;
    uint4* dst = reinterpret_cast<uint4*>(T + off);
    const uint4* sv = reinterpret_cast<const uint4*>(outv);
    dst[0] = sv[0];
    dst[1] = sv[1];
}

extern "C" void kernel_launch(void* const* d_in, const int* in_sizes, int n_in,
                              void* d_out, int out_size, void* d_ws, size_t ws_size,
                              hipStream_t stream) {
    const float* x     = (const float*)d_in[0];   // (4,2048,1024)
    const float* w_qkv = (const float*)d_in[1];   // (3072,1024)
    const float* b_qkv = (const float*)d_in[2];   // (3072,)
    const float* w_out = (const float*)d_in[3];   // (1024,1024)
    const float* b_out = (const float*)d_in[4];   // (1024,)
    float* out = (float*)d_out;                   // (4,2048,1024) fp32

    const int M = 8192, E = 3072, K = 1024, D = 1024;

    // ws: [0, 50.33MB) qkv bf16 -> later W2b; [50.33MB, 67.1MB) T bf16.
    // d_out scratch: W1b (w_qkv bf16) until GEMM2 overwrites.
    bf16* qkv = (bf16*)d_ws;
    bf16* T   = qkv + (size_t)M * E;
    bf16* W2b = qkv;
    bf16* W1b = (bf16*)d_out;

    dim3 blk(256);

    // 1) w_qkv fp32 -> bf16 (d_out scratch)
    cvt_f32_bf16<<<dim3(E * K / 4 / 256), blk, 0, stream>>>(w_qkv, W1b, E * K / 4);
    // 2) QKV projection, fused x fp32->bf16 A-staging. Grid 768 = 3.0 CU rounds.
    gemmf<true, bf16><<<dim3((M / 128) * (E / 256)), dim3(512), 0, stream>>>(
        (const void*)x, W1b, b_qkv, qkv, M, E, K, E / 256);
    // 3) per-token heads-axis attention + scrambled reshape -> bf16 T
    attn_kernel<<<dim3(M / 4), blk, 0, stream>>>(qkv, T);
    // 4) w_out fp32 -> bf16 (dead qkv region)
    cvt_f32_bf16<<<dim3(D * K / 4 / 256), blk, 0, stream>>>(w_out, W2b, D * K / 4);
    // 5) output projection (bf16 A via gload_lds). Grid 256 = 1.0 CU round.
    gemmf<false, float><<<dim3((M / 128) * (D / 256)), dim3(512), 0, stream>>>(
        (const void*)T, W2b, b_out, out, M, D, K, D / 256);
}

// Round 12
// 116.852 us; speedup vs baseline: 1.2673x; 1.2673x over previous
//
#include <hip/hip_runtime.h>
#include <hip/hip_bf16.h>

// N=4, S=2048, D_MODEL=1024, HEADS=16, HEAD_DIM=64. M = 8192 tokens, E = 3072.

typedef __hip_bfloat16 bf16;
using bf16x8 = __attribute__((ext_vector_type(8))) short;
using f32x4  = __attribute__((ext_vector_type(4))) float;

__device__ __forceinline__ float b2f(unsigned short u) {
    return __uint_as_float(((unsigned)u) << 16);
}
__device__ __forceinline__ unsigned short f2b(float f) {
    bf16 h = __float2bfloat16(f);
    return *reinterpret_cast<unsigned short*>(&h);
}
__device__ __forceinline__ void store1(float* p, float v) { *p = v; }
__device__ __forceinline__ void store1(bf16* p, float v) { *p = __float2bfloat16(v); }

// async global->LDS, 16B per lane. LDS dest = wave-uniform base + lane*16.
__device__ __forceinline__ void gload_lds16(const bf16* g, bf16* l) {
    __builtin_amdgcn_global_load_lds(
        (const __attribute__((address_space(1))) void*)g,
        (__attribute__((address_space(3))) void*)l, 16, 0, 0);
}

#define BAR()   __builtin_amdgcn_s_barrier()
#define LGKM(N) asm volatile("s_waitcnt lgkmcnt(" #N ")" ::: "memory")
#define VMC(N)  asm volatile("s_waitcnt vmcnt(" #N ")" ::: "memory")

// ============================================================================
// GEMM1: 128(M) x 384(N) tile, BK=64, 2-buf (128KB), min-sync r10 schedule.
// 512 thr = 8 waves (2Mx4N), wave out 64x96 = acc[4][6]. Grid 64*8=512 = 2.0
// exact CU rounds. Port model: 224 LDS ops/tile vs r10's 176 per 1.5x FLOPs.
// Swizzle (verified r7-r10, 0 conflicts): read byte ^= (row&7)<<4; inverse on
// GLOBAL k (kel = ((lane&7)^(lane>>3))*8); linear gload_lds dest.
// Per-tile: { stage(t+1) 8 gloads [issued first, lands ~full tile later];
//   20 ds_reads (kk0 10, kk1 10); LGKM(10) MFMA kk0 (24);
//   LGKM(0) MFMA kk1 (24); VMC(0) [t+1 landed, wait~free]; BAR }
// Hazard: stage(t+1) writes buf^1 whose tile-(t-1) reads all retired before
// BAR(t-1) (LGKM(0) precedes final MFMA) -> BAR orders write-after-read.
// ============================================================================
__global__ __launch_bounds__(512, 2)
void gemm384(const bf16* __restrict__ A, const bf16* __restrict__ B,
             const float* __restrict__ bias, bf16* __restrict__ C,
             int M, int N, int K, int gx) {
    __shared__ alignas(1024) bf16 smem[2][512 * 64];  // A[0:8192) B[8192:32768) elems

    const int t    = threadIdx.x;
    const int lane = t & 63;
    const int wid  = t >> 6;
    const int wr   = wid >> 2;   // 0..1
    const int wc   = wid & 3;    // 0..3

    const int nwg = gridDim.x;
    const int bid = blockIdx.x;
    const int wg  = (bid & 7) * (nwg >> 3) + (bid >> 3);
    const int m0  = (wg / gx) * 128;
    const int n0  = (wg % gx) * 384;
    const int nt  = K / 64;

    const int srow = lane >> 3;
    const int kel  = ((lane & 7) ^ (lane >> 3)) * 8;

    auto stageA = [&](int tt) {            // 16 rows/wave = 2 gloads
        if (tt >= nt) return;
        bf16* lp = &smem[tt & 1][wid * 1024];
        const bf16* gp = A + (size_t)(m0 + wid * 16 + srow) * K + tt * 64 + kel;
        gload_lds16(gp, lp);
        gload_lds16(gp + (size_t)8 * K, lp + 512);
    };
    auto stageB = [&](int tt) {            // 48 rows/wave = 6 gloads
        if (tt >= nt) return;
        bf16* lp = &smem[tt & 1][8192 + wid * 3072];
        const bf16* gp = B + (size_t)(n0 + wid * 48 + srow) * K + tt * 64 + kel;
#pragma unroll
        for (int i = 0; i < 6; ++i)
            gload_lds16(gp + (size_t)(i * 8) * K, lp + i * 512);
    };

    const int arow_base = wr * 64 + (lane & 15);
    const int brow_base = wc * 96 + (lane & 15);
    const int kqb       = (lane >> 4) * 16;
    auto LDA = [&](int buf, int kk, int m) -> bf16x8 {
        const int row = arow_base + m * 16;
        const int ab  = row * 128 + ((kk * 64 + kqb) ^ ((row & 7) << 4));
        return *(const bf16x8*)((const char*)&smem[buf][0] + ab);
    };
    auto LDB = [&](int buf, int kk, int n) -> bf16x8 {
        const int row = brow_base + n * 16;
        const int bb  = 16384 + row * 128 + ((kk * 64 + kqb) ^ ((row & 7) << 4));
        return *(const bf16x8*)((const char*)&smem[buf][0] + bb);
    };

    f32x4 acc[4][6] = {};
    bf16x8 af0[4], bv0[6], af1[4], bv1[6];

    // prologue: stage t0; drain; BAR
    stageA(0); stageB(0);
    VMC(0);
    BAR();

    for (int tt = 0; tt < nt; ++tt) {
        const int buf = tt & 1;

        // stage t+1 first (lands during this tile's compute)
        stageA(tt + 1); stageB(tt + 1);

        // 20 frag reads: kk0 (oldest 10), then kk1
#pragma unroll
        for (int m = 0; m < 4; ++m) af0[m] = LDA(buf, 0, m);
#pragma unroll
        for (int n = 0; n < 6; ++n) bv0[n] = LDB(buf, 0, n);
#pragma unroll
        for (int m = 0; m < 4; ++m) af1[m] = LDA(buf, 1, m);
#pragma unroll
        for (int n = 0; n < 6; ++n) bv1[n] = LDB(buf, 1, n);

        LGKM(10);                        // kk0 ready; kk1 flies under MFMA kk0
        __builtin_amdgcn_s_setprio(1);
#pragma unroll
        for (int m = 0; m < 4; ++m)
#pragma unroll
            for (int n = 0; n < 6; ++n)
                acc[m][n] = __builtin_amdgcn_mfma_f32_16x16x32_bf16(
                    af0[m], bv0[n], acc[m][n], 0, 0, 0);
        __builtin_amdgcn_s_setprio(0);
        LGKM(0);
        __builtin_amdgcn_s_setprio(1);
#pragma unroll
        for (int m = 0; m < 4; ++m)
#pragma unroll
            for (int n = 0; n < 6; ++n)
                acc[m][n] = __builtin_amdgcn_mfma_f32_16x16x32_bf16(
                    af1[m], bv1[n], acc[m][n], 0, 0, 0);
        __builtin_amdgcn_s_setprio(0);

        VMC(0);                          // t+1 landed (issued a full tile ago)
        BAR();
    }

    // epilogue
#pragma unroll
    for (int m = 0; m < 4; ++m) {
        const int row = m0 + wr * 64 + m * 16 + (lane >> 4) * 4;
#pragma unroll
        for (int n = 0; n < 6; ++n) {
            const int col = n0 + wc * 96 + n * 16 + (lane & 15);
            const float bval = bias[col];
#pragma unroll
            for (int r = 0; r < 4; ++r)
                store1(&C[(size_t)(row + r) * N + col], acc[m][n][r] + bval);
        }
    }
}

// ============================================================================
// GEMM2: r10 min-sync 128x256, BK=64, 3-buf (proven, 0 conflicts).
// ============================================================================
template <typename CT>
__global__ __launch_bounds__(512, 2)
void gemm1b(const bf16* __restrict__ A, const bf16* __restrict__ B,
            const float* __restrict__ bias, CT* __restrict__ C,
            int M, int N, int K, int gx) {
    __shared__ alignas(1024) bf16 smem[3][384 * 64];

    const int t    = threadIdx.x;
    const int lane = t & 63;
    const int wid  = t >> 6;
    const int wr   = wid >> 2;
    const int wc   = wid & 3;

    const int nwg = gridDim.x;
    const int bid = blockIdx.x;
    const int wg  = (bid & 7) * (nwg >> 3) + (bid >> 3);
    const int m0  = (wg / gx) * 128;
    const int n0  = (wg % gx) * 256;
    const int nt  = K / 64;

    const int srow = lane >> 3;
    const int kel  = ((lane & 7) ^ (lane >> 3)) * 8;

    auto stageA = [&](int tt) {
        if (tt >= nt) return;
        bf16* lp = &smem[tt % 3][wid * 1024];
        const bf16* gp = A + (size_t)(m0 + wid * 16 + srow) * K + tt * 64 + kel;
        gload_lds16(gp, lp);
        gload_lds16(gp + (size_t)8 * K, lp + 512);
    };
    auto stageB = [&](int tt, int h) {
        if (tt >= nt) return;
        bf16* lp = &smem[tt % 3][8192 + h * 8192 + wid * 1024];
        const bf16* gp = B + (size_t)(n0 + h * 128 + wid * 16 + srow) * K + tt * 64 + kel;
        gload_lds16(gp, lp);
        gload_lds16(gp + (size_t)8 * K, lp + 512);
    };

    const int arow_base = wr * 64 + (lane & 15);
    const int brow_base = wc * 64 + (lane & 15);
    const int kqb       = (lane >> 4) * 16;
    auto LDA = [&](int buf, int kk, int m) -> bf16x8 {
        const int row = arow_base + m * 16;
        const int ab  = row * 128 + ((kk * 64 + kqb) ^ ((row & 7) << 4));
        return *(const bf16x8*)((const char*)&smem[buf][0] + ab);
    };
    auto LDB = [&](int buf, int kk, int n) -> bf16x8 {
        const int row = brow_base + n * 16;
        const int bb  = 16384 + row * 128 + ((kk * 64 + kqb) ^ ((row & 7) << 4));
        return *(const bf16x8*)((const char*)&smem[buf][0] + bb);
    };

    f32x4 acc[4][4] = {};
    bf16x8 af0[4], bf0[4], af1[4], bf1[4];

    stageA(0); stageB(0, 0); stageB(0, 1);
    stageA(1); stageB(1, 0); stageB(1, 1);
    VMC(6);
    BAR();

    for (int tt = 0; tt < nt; ++tt) {
        const int buf = tt % 3;

#pragma unroll
        for (int m = 0; m < 4; ++m) af0[m] = LDA(buf, 0, m);
#pragma unroll
        for (int n = 0; n < 4; ++n) bf0[n] = LDB(buf, 0, n);
#pragma unroll
        for (int m = 0; m < 4; ++m) af1[m] = LDA(buf, 1, m);
#pragma unroll
        for (int n = 0; n < 4; ++n) bf1[n] = LDB(buf, 1, n);
        stageA(tt + 2); stageB(tt + 2, 0); stageB(tt + 2, 1);
        LGKM(8);
        __builtin_amdgcn_s_setprio(1);
#pragma unroll
        for (int m = 0; m < 4; ++m)
#pragma unroll
            for (int n = 0; n < 4; ++n)
                acc[m][n] = __builtin_amdgcn_mfma_f32_16x16x32_bf16(
                    af0[m], bf0[n], acc[m][n], 0, 0, 0);
        __builtin_amdgcn_s_setprio(0);
        LGKM(0);
        __builtin_amdgcn_s_setprio(1);
#pragma unroll
        for (int m = 0; m < 4; ++m)
#pragma unroll
            for (int n = 0; n < 4; ++n)
                acc[m][n] = __builtin_amdgcn_mfma_f32_16x16x32_bf16(
                    af1[m], bf1[n], acc[m][n], 0, 0, 0);
        __builtin_amdgcn_s_setprio(0);
        if (tt < nt - 2) { VMC(6); } else { VMC(0); }
        BAR();
    }

#pragma unroll
    for (int m = 0; m < 4; ++m) {
        const int row = m0 + wr * 64 + m * 16 + (lane >> 4) * 4;
#pragma unroll
        for (int n = 0; n < 4; ++n) {
            const int col = n0 + wc * 64 + n * 16 + (lane & 15);
            const float bval = bias[col];
#pragma unroll
            for (int r = 0; r < 4; ++r)
                store1(&C[(size_t)(row + r) * N + col], acc[m][n][r] + bval);
        }
    }
}

// ---- fused fp32 -> bf16 conversion of TWO buffers, 4 elems/thread ----
__global__ __launch_bounds__(256)
void cvt2_f32_bf16(const float* __restrict__ in1, bf16* __restrict__ out1, int n1,
                   const float* __restrict__ in2, bf16* __restrict__ out2, int n2) {
    int i = blockIdx.x * 256 + threadIdx.x;
    const float* in;
    bf16* out;
    if (i < n1) { in = in1; out = out1; }
    else        { in = in2; out = out2; i -= n1; if (i >= n2) return; }
    float4 v = ((const float4*)in)[i];
    ushort4 o = {f2b(v.x), f2b(v.y), f2b(v.z), f2b(v.w)};
    ((ushort4*)out)[i] = o;
}

// ---- fp32 -> bf16 conversion, 4 elems/thread ----
__global__ __launch_bounds__(256)
void cvt_f32_bf16(const float* __restrict__ in, bf16* __restrict__ out, int n4) {
    int i = blockIdx.x * 256 + threadIdx.x;
    if (i >= n4) return;
    float4 v = ((const float4*)in)[i];
    ushort4 o = {f2b(v.x), f2b(v.y), f2b(v.z), f2b(v.w)};
    ((ushort4*)out)[i] = o;
}

// ---- Per-token attention over heads axis + scrambled T write ----
__global__ __launch_bounds__(256)
void attn_kernel(const bf16* __restrict__ qkv, bf16* __restrict__ T) {
    __shared__ float lds[4][48 * 68];

    const int wave = threadIdx.x >> 6;
    const int lane = threadIdx.x & 63;
    const int token = blockIdx.x * 4 + wave;
    const int n = token >> 11;
    const int s = token & 2047;

    float* L = lds[wave];
    const bf16* src = qkv + (size_t)token * 3072;

#pragma unroll
    for (int i = 0; i < 6; ++i) {
        int idx = i * 64 + lane;
        uint4 v = *reinterpret_cast<const uint4*>(src + (size_t)idx * 8);
        int e0 = idx * 8;
        float* dst = &L[(e0 >> 6) * 68 + (e0 & 63)];
        float4 a, b;
        a.x = b2f((unsigned short)(v.x & 0xffff));
        a.y = b2f((unsigned short)(v.x >> 16));
        a.z = b2f((unsigned short)(v.y & 0xffff));
        a.w = b2f((unsigned short)(v.y >> 16));
        b.x = b2f((unsigned short)(v.z & 0xffff));
        b.y = b2f((unsigned short)(v.z >> 16));
        b.z = b2f((unsigned short)(v.w & 0xffff));
        b.w = b2f((unsigned short)(v.w >> 16));
        *(float4*)dst = a;
        *(float4*)(dst + 4) = b;
    }
    __syncthreads();

    const int q0 = lane & 15;
    const int g  = lane >> 4;

    float e[4] = {0.f, 0.f, 0.f, 0.f};
    const float* Qr = &L[q0 * 68];
    const float* K0 = &L[(16 + g * 4) * 68];
#pragma unroll
    for (int d = 0; d < 64; d += 4) {
        float4 q4 = *(const float4*)(Qr + d);
#pragma unroll
        for (int j = 0; j < 4; ++j) {
            float4 k4 = *(const float4*)(K0 + j * 68 + d);
            e[j] += q4.x * k4.x + q4.y * k4.y + q4.z * k4.z + q4.w * k4.w;
        }
    }
#pragma unroll
    for (int j = 0; j < 4; ++j) e[j] *= 0.125f;

    float m = fmaxf(fmaxf(e[0], e[1]), fmaxf(e[2], e[3]));
    m = fmaxf(m, __shfl_xor(m, 16));
    m = fmaxf(m, __shfl_xor(m, 32));
    float p[4], sum = 0.f;
#pragma unroll
    for (int j = 0; j < 4; ++j) { p[j] = __expf(e[j] - m); sum += p[j]; }
    sum += __shfl_xor(sum, 16);
    sum += __shfl_xor(sum, 32);
    const float inv = 1.0f / sum;

    float prow[16];
#pragma unroll
    for (int j = 0; j < 4; ++j) {
        prow[g * 4 + j]         = p[j] * inv;
        prow[((g ^ 1) * 4) + j] = __shfl_xor(p[j], 16) * inv;
        prow[((g ^ 2) * 4) + j] = __shfl_xor(p[j], 32) * inv;
        prow[((g ^ 3) * 4) + j] = __shfl_xor(p[j], 48) * inv;
    }

    const int d0 = g * 16;
    float4 o4[4] = {};
#pragma unroll
    for (int k = 0; k < 16; ++k) {
        const float p1 = prow[k];
        const float* Vr = &L[(32 + k) * 68 + d0];
#pragma unroll
        for (int c = 0; c < 4; ++c) {
            float4 v = *(const float4*)(Vr + c * 4);
            o4[c].x += p1 * v.x; o4[c].y += p1 * v.y;
            o4[c].z += p1 * v.z; o4[c].w += p1 * v.w;
        }
    }
    unsigned short outv[16];
#pragma unroll
    for (int c = 0; c < 4; ++c) {
        outv[c * 4 + 0] = f2b(o4[c].x); outv[c * 4 + 1] = f2b(o4[c].y);
        outv[c * 4 + 2] = f2b(o4[c].z); outv[c * 4 + 3] = f2b(o4[c].w);
    }
    const int sp = q0 * 128 + (s >> 4);
    size_t off = ((size_t)n * 2048 + sp) * 1024 + (size_t)(s & 15) * 64 + d0;
    uint4* dst = reinterpret_cast<uint4*>(T + off);
    const uint4* sv = reinterpret_cast<const uint4*>(outv);
    dst[0] = sv[0];
    dst[1] = sv[1];
}

extern "C" void kernel_launch(void* const* d_in, const int* in_sizes, int n_in,
                              void* d_out, int out_size, void* d_ws, size_t ws_size,
                              hipStream_t stream) {
    const float* x     = (const float*)d_in[0];   // (4,2048,1024)
    const float* w_qkv = (const float*)d_in[1];   // (3072,1024)
    const float* b_qkv = (const float*)d_in[2];   // (3072,)
    const float* w_out = (const float*)d_in[3];   // (1024,1024)
    const float* b_out = (const float*)d_in[4];   // (1024,)
    float* out = (float*)d_out;                   // (4,2048,1024) fp32

    const int M = 8192, E = 3072, K = 1024, D = 1024;

    // ws: [0, 50.33M) qkv bf16 -> later W2b; [50.33M, 67.11M) T bf16.
    // d_out doubles as scratch until GEMM2 rewrites it: W1b then X16.
    bf16* qkv = (bf16*)d_ws;
    bf16* T   = qkv + (size_t)M * E;
    bf16* W2b = qkv;
    bf16* W1b = (bf16*)d_out;
    bf16* X16 = W1b + (size_t)E * K;

    dim3 blk(256);
    const int n1 = M * K / 4, n2 = E * K / 4;

    // 1) x and w_qkv fp32 -> bf16 (one dispatch, d_out scratch)
    cvt2_f32_bf16<<<dim3((n1 + n2) / 256), blk, 0, stream>>>(
        x, X16, n1, w_qkv, W1b, n2);
    // 2) QKV projection: 128x384 tiles, grid 64*8=512 = 2.0 exact CU rounds
    gemm384<<<dim3((M / 128) * (E / 384)), dim3(512), 0, stream>>>(
        X16, W1b, b_qkv, qkv, M, E, K, E / 384);
    // 3) per-token heads-axis attention + scrambled reshape -> bf16 T
    attn_kernel<<<dim3(M / 4), blk, 0, stream>>>(qkv, T);
    // 4) w_out fp32 -> bf16 (dead qkv region)
    cvt_f32_bf16<<<dim3(D * K / 4 / 256), blk, 0, stream>>>(w_out, W2b, D * K / 4);
    // 5) output projection: r10 min-sync 128x256, grid 256 = 1.0 CU round
    gemm1b<float><<<dim3((M / 128) * (D / 256)), dim3(512), 0, stream>>>(
        T, W2b, b_out, out, M, D, K, D / 256);
}

// Round 13
// 116.641 us; speedup vs baseline: 1.2696x; 1.0018x over previous
//
#include <hip/hip_runtime.h>
#include <hip/hip_bf16.h>

// N=4, S=2048, D_MODEL=1024, HEADS=16, HEAD_DIM=64. M = 8192 tokens, E = 3072.

typedef __hip_bfloat16 bf16;
using bf16x8 = __attribute__((ext_vector_type(8))) short;
using f32x4  = __attribute__((ext_vector_type(4))) float;

__device__ __forceinline__ float b2f(unsigned short u) {
    return __uint_as_float(((unsigned)u) << 16);
}
__device__ __forceinline__ unsigned short f2b(float f) {
    bf16 h = __float2bfloat16(f);
    return *reinterpret_cast<unsigned short*>(&h);
}
__device__ __forceinline__ void store1(float* p, float v) { *p = v; }
__device__ __forceinline__ void store1(bf16* p, float v) { *p = __float2bfloat16(v); }

// async global->LDS, 16B per lane. LDS dest = wave-uniform base + lane*16.
__device__ __forceinline__ void gload_lds16(const bf16* g, bf16* l) {
    __builtin_amdgcn_global_load_lds(
        (const __attribute__((address_space(1))) void*)g,
        (__attribute__((address_space(3))) void*)l, 16, 0, 0);
}

#define BAR()   __builtin_amdgcn_s_barrier()
#define LGKM(N) asm volatile("s_waitcnt lgkmcnt(" #N ")" ::: "memory")
#define VMC(N)  asm volatile("s_waitcnt vmcnt(" #N ")" ::: "memory")

// ============================================================================
// Unified min-sync GEMM (r12 gemm384 schedule). C = A*B^T + bias. K mult 64.
// Tile 128(M) x 64*NF(N), BK=64, 2-buf. 512 thr = 8 waves (2Mx4N), wave out
// 64 x 16*NF = acc[4][NF]. NF=6: GEMM1 (grid 512 = 2.0 CU rounds, 128KB LDS).
// NF=4: GEMM2 (grid 256 = 1.0 round, 96KB LDS).
// Swizzle (verified r7-r12, 0 conflicts): read byte ^= (row&7)<<4; inverse on
// GLOBAL k (kel = ((lane&7)^(lane>>3))*8); linear gload_lds dest.
// Per-tile (reads issued FIRST so LGKM head isn't behind VMEM issue):
//   { 2*(4+NF) ds_reads (kk0 first); stage(t+1) 2+NF gloads;
//     LGKM(4+NF) MFMA kk0; LGKM(0) MFMA kk1; VMC(0) [t+1 landed, issued a
//     full tile ago => ~free]; BAR }
// Hazard: stage(t+1) writes buf^1 whose tile-(t-1) reads all retired before
// BAR(t-1) (LGKM(0) precedes final MFMA) -> BAR orders write-after-read.
// ============================================================================
template <int NF, typename CT>
__global__ __launch_bounds__(512, 2)
void gemm_u(const bf16* __restrict__ A, const bf16* __restrict__ B,
            const float* __restrict__ bias, CT* __restrict__ C,
            int M, int N, int K, int gx) {
    __shared__ alignas(1024) bf16 smem[2][(128 + 64 * NF) * 64];

    const int t    = threadIdx.x;
    const int lane = t & 63;
    const int wid  = t >> 6;
    const int wr   = wid >> 2;   // 0..1
    const int wc   = wid & 3;    // 0..3

    const int nwg = gridDim.x;
    const int bid = blockIdx.x;
    const int wg  = (bid & 7) * (nwg >> 3) + (bid >> 3);
    const int m0  = (wg / gx) * 128;
    const int n0  = (wg % gx) * (64 * NF);
    const int nt  = K / 64;

    const int srow = lane >> 3;
    const int kel  = ((lane & 7) ^ (lane >> 3)) * 8;

    auto stageA = [&](int tt) {            // 16 rows/wave = 2 gloads
        if (tt >= nt) return;
        bf16* lp = &smem[tt & 1][wid * 1024];
        const bf16* gp = A + (size_t)(m0 + wid * 16 + srow) * K + tt * 64 + kel;
        gload_lds16(gp, lp);
        gload_lds16(gp + (size_t)8 * K, lp + 512);
    };
    auto stageB = [&](int tt) {            // 8*NF rows/wave = NF gloads
        if (tt >= nt) return;
        bf16* lp = &smem[tt & 1][8192 + wid * (NF * 512)];
        const bf16* gp = B + (size_t)(n0 + wid * 8 * NF + srow) * K + tt * 64 + kel;
#pragma unroll
        for (int i = 0; i < NF; ++i)
            gload_lds16(gp + (size_t)(i * 8) * K, lp + i * 512);
    };

    const int arow_base = wr * 64 + (lane & 15);
    const int brow_base = wc * (16 * NF) + (lane & 15);
    const int kqb       = (lane >> 4) * 16;
    auto LDA = [&](int buf, int kk, int m) -> bf16x8 {
        const int row = arow_base + m * 16;
        const int ab  = row * 128 + ((kk * 64 + kqb) ^ ((row & 7) << 4));
        return *(const bf16x8*)((const char*)&smem[buf][0] + ab);
    };
    auto LDB = [&](int buf, int kk, int n) -> bf16x8 {
        const int row = brow_base + n * 16;
        const int bb  = 16384 + row * 128 + ((kk * 64 + kqb) ^ ((row & 7) << 4));
        return *(const bf16x8*)((const char*)&smem[buf][0] + bb);
    };

    f32x4 acc[4][NF] = {};
    bf16x8 af0[4], bv0[NF], af1[4], bv1[NF];

    // prologue
    stageA(0); stageB(0);
    VMC(0);
    BAR();

    for (int tt = 0; tt < nt; ++tt) {
        const int buf = tt & 1;

        // frag reads first: kk0 (oldest 4+NF), then kk1
#pragma unroll
        for (int m = 0; m < 4; ++m) af0[m] = LDA(buf, 0, m);
#pragma unroll
        for (int n = 0; n < NF; ++n) bv0[n] = LDB(buf, 0, n);
#pragma unroll
        for (int m = 0; m < 4; ++m) af1[m] = LDA(buf, 1, m);
#pragma unroll
        for (int n = 0; n < NF; ++n) bv1[n] = LDB(buf, 1, n);

        // stage t+1 (lands during this tile's compute)
        stageA(tt + 1); stageB(tt + 1);

        if constexpr (NF == 6) { LGKM(10); } else { LGKM(8); }
        __builtin_amdgcn_s_setprio(1);
#pragma unroll
        for (int m = 0; m < 4; ++m)
#pragma unroll
            for (int n = 0; n < NF; ++n)
                acc[m][n] = __builtin_amdgcn_mfma_f32_16x16x32_bf16(
                    af0[m], bv0[n], acc[m][n], 0, 0, 0);
        __builtin_amdgcn_s_setprio(0);
        LGKM(0);
        __builtin_amdgcn_s_setprio(1);
#pragma unroll
        for (int m = 0; m < 4; ++m)
#pragma unroll
            for (int n = 0; n < NF; ++n)
                acc[m][n] = __builtin_amdgcn_mfma_f32_16x16x32_bf16(
                    af1[m], bv1[n], acc[m][n], 0, 0, 0);
        __builtin_amdgcn_s_setprio(0);

        VMC(0);                          // t+1 landed (issued a full tile ago)
        BAR();
    }

    // epilogue
#pragma unroll
    for (int m = 0; m < 4; ++m) {
        const int row = m0 + wr * 64 + m * 16 + (lane >> 4) * 4;
#pragma unroll
        for (int n = 0; n < NF; ++n) {
            const int col = n0 + wc * (16 * NF) + n * 16 + (lane & 15);
            const float bval = bias[col];
#pragma unroll
            for (int r = 0; r < 4; ++r)
                store1(&C[(size_t)(row + r) * N + col], acc[m][n][r] + bval);
        }
    }
}

// ---- fused fp32 -> bf16 conversion of TWO buffers, 4 elems/thread ----
__global__ __launch_bounds__(256)
void cvt2_f32_bf16(const float* __restrict__ in1, bf16* __restrict__ out1, int n1,
                   const float* __restrict__ in2, bf16* __restrict__ out2, int n2) {
    int i = blockIdx.x * 256 + threadIdx.x;
    const float* in;
    bf16* out;
    if (i < n1) { in = in1; out = out1; }
    else        { in = in2; out = out2; i -= n1; if (i >= n2) return; }
    float4 v = ((const float4*)in)[i];
    ushort4 o = {f2b(v.x), f2b(v.y), f2b(v.z), f2b(v.w)};
    ((ushort4*)out)[i] = o;
}

// ---- fp32 -> bf16 conversion, 4 elems/thread ----
__global__ __launch_bounds__(256)
void cvt_f32_bf16(const float* __restrict__ in, bf16* __restrict__ out, int n4) {
    int i = blockIdx.x * 256 + threadIdx.x;
    if (i >= n4) return;
    float4 v = ((const float4*)in)[i];
    ushort4 o = {f2b(v.x), f2b(v.y), f2b(v.z), f2b(v.w)};
    ((ushort4*)out)[i] = o;
}

// ---- Per-token attention over heads axis + scrambled T write ----
__global__ __launch_bounds__(256)
void attn_kernel(const bf16* __restrict__ qkv, bf16* __restrict__ T) {
    __shared__ float lds[4][48 * 68];

    const int wave = threadIdx.x >> 6;
    const int lane = threadIdx.x & 63;
    const int token = blockIdx.x * 4 + wave;
    const int n = token >> 11;
    const int s = token & 2047;

    float* L = lds[wave];
    const bf16* src = qkv + (size_t)token * 3072;

#pragma unroll
    for (int i = 0; i < 6; ++i) {
        int idx = i * 64 + lane;
        uint4 v = *reinterpret_cast<const uint4*>(src + (size_t)idx * 8);
        int e0 = idx * 8;
        float* dst = &L[(e0 >> 6) * 68 + (e0 & 63)];
        float4 a, b;
        a.x = b2f((unsigned short)(v.x & 0xffff));
        a.y = b2f((unsigned short)(v.x >> 16));
        a.z = b2f((unsigned short)(v.y & 0xffff));
        a.w = b2f((unsigned short)(v.y >> 16));
        b.x = b2f((unsigned short)(v.z & 0xffff));
        b.y = b2f((unsigned short)(v.z >> 16));
        b.z = b2f((unsigned short)(v.w & 0xffff));
        b.w = b2f((unsigned short)(v.w >> 16));
        *(float4*)dst = a;
        *(float4*)(dst + 4) = b;
    }
    __syncthreads();

    const int q0 = lane & 15;
    const int g  = lane >> 4;

    float e[4] = {0.f, 0.f, 0.f, 0.f};
    const float* Qr = &L[q0 * 68];
    const float* K0 = &L[(16 + g * 4) * 68];
#pragma unroll
    for (int d = 0; d < 64; d += 4) {
        float4 q4 = *(const float4*)(Qr + d);
#pragma unroll
        for (int j = 0; j < 4; ++j) {
            float4 k4 = *(const float4*)(K0 + j * 68 + d);
            e[j] += q4.x * k4.x + q4.y * k4.y + q4.z * k4.z + q4.w * k4.w;
        }
    }
#pragma unroll
    for (int j = 0; j < 4; ++j) e[j] *= 0.125f;

    float m = fmaxf(fmaxf(e[0], e[1]), fmaxf(e[2], e[3]));
    m = fmaxf(m, __shfl_xor(m, 16));
    m = fmaxf(m, __shfl_xor(m, 32));
    float p[4], sum = 0.f;
#pragma unroll
    for (int j = 0; j < 4; ++j) { p[j] = __expf(e[j] - m); sum += p[j]; }
    sum += __shfl_xor(sum, 16);
    sum += __shfl_xor(sum, 32);
    const float inv = 1.0f / sum;

    float prow[16];
#pragma unroll
    for (int j = 0; j < 4; ++j) {
        prow[g * 4 + j]         = p[j] * inv;
        prow[((g ^ 1) * 4) + j] = __shfl_xor(p[j], 16) * inv;
        prow[((g ^ 2) * 4) + j] = __shfl_xor(p[j], 32) * inv;
        prow[((g ^ 3) * 4) + j] = __shfl_xor(p[j], 48) * inv;
    }

    const int d0 = g * 16;
    float4 o4[4] = {};
#pragma unroll
    for (int k = 0; k < 16; ++k) {
        const float p1 = prow[k];
        const float* Vr = &L[(32 + k) * 68 + d0];
#pragma unroll
        for (int c = 0; c < 4; ++c) {
            float4 v = *(const float4*)(Vr + c * 4);
            o4[c].x += p1 * v.x; o4[c].y += p1 * v.y;
            o4[c].z += p1 * v.z; o4[c].w += p1 * v.w;
        }
    }
    unsigned short outv[16];
#pragma unroll
    for (int c = 0; c < 4; ++c) {
        outv[c * 4 + 0] = f2b(o4[c].x); outv[c * 4 + 1] = f2b(o4[c].y);
        outv[c * 4 + 2] = f2b(o4[c].z); outv[c * 4 + 3] = f2b(o4[c].w);
    }
    const int sp = q0 * 128 + (s >> 4);
    size_t off = ((size_t)n * 2048 + sp) * 1024 + (size_t)(s & 15) * 64 + d0;
    uint4* dst = reinterpret_cast<uint4*>(T + off);
    const uint4* sv = reinterpret_cast<const uint4*>(outv);
    dst[0] = sv[0];
    dst[1] = sv[1];
}

extern "C" void kernel_launch(void* const* d_in, const int* in_sizes, int n_in,
                              void* d_out, int out_size, void* d_ws, size_t ws_size,
                              hipStream_t stream) {
    const float* x     = (const float*)d_in[0];   // (4,2048,1024)
    const float* w_qkv = (const float*)d_in[1];   // (3072,1024)
    const float* b_qkv = (const float*)d_in[2];   // (3072,)
    const float* w_out = (const float*)d_in[3];   // (1024,1024)
    const float* b_out = (const float*)d_in[4];   // (1024,)
    float* out = (float*)d_out;                   // (4,2048,1024) fp32

    const int M = 8192, E = 3072, K = 1024, D = 1024;

    // ws: [0, 50.33M) qkv bf16 -> later W2b; [50.33M, 67.11M) T bf16.
    // d_out doubles as scratch until GEMM2 rewrites it: W1b then X16.
    bf16* qkv = (bf16*)d_ws;
    bf16* T   = qkv + (size_t)M * E;
    bf16* W2b = qkv;
    bf16* W1b = (bf16*)d_out;
    bf16* X16 = W1b + (size_t)E * K;

    dim3 blk(256);
    const int n1 = M * K / 4, n2 = E * K / 4;

    // 1) x and w_qkv fp32 -> bf16 (one dispatch, d_out scratch)
    cvt2_f32_bf16<<<dim3((n1 + n2) / 256), blk, 0, stream>>>(
        x, X16, n1, w_qkv, W1b, n2);
    // 2) QKV projection: 128x384 tiles, grid 64*8=512 = 2.0 exact CU rounds
    gemm_u<6, bf16><<<dim3((M / 128) * (E / 384)), dim3(512), 0, stream>>>(
        X16, W1b, b_qkv, qkv, M, E, K, E / 384);
    // 3) per-token heads-axis attention + scrambled reshape -> bf16 T
    attn_kernel<<<dim3(M / 4), blk, 0, stream>>>(qkv, T);
    // 4) w_out fp32 -> bf16 (dead qkv region)
    cvt_f32_bf16<<<dim3(D * K / 4 / 256), blk, 0, stream>>>(w_out, W2b, D * K / 4);
    // 5) output projection: 128x256 tiles, grid 64*4=256 = 1.0 exact CU round
    gemm_u<4, float><<<dim3((M / 128) * (D / 256)), dim3(512), 0, stream>>>(
        T, W2b, b_out, out, M, D, K, D / 256);
}

// Round 14
// 114.946 us; speedup vs baseline: 1.2883x; 1.0147x over previous
//
#include <hip/hip_runtime.h>
#include <hip/hip_bf16.h>

// N=4, S=2048, D_MODEL=1024, HEADS=16, HEAD_DIM=64. M = 8192 tokens, E = 3072.

typedef __hip_bfloat16 bf16;
using bf16x8 = __attribute__((ext_vector_type(8))) short;
using f32x4  = __attribute__((ext_vector_type(4))) float;

__device__ __forceinline__ float b2f(unsigned short u) {
    return __uint_as_float(((unsigned)u) << 16);
}
__device__ __forceinline__ unsigned short f2b(float f) {
    bf16 h = __float2bfloat16(f);
    return *reinterpret_cast<unsigned short*>(&h);
}
__device__ __forceinline__ void store1(float* p, float v) { *p = v; }
__device__ __forceinline__ void store1(bf16* p, float v) { *p = __float2bfloat16(v); }

// async global->LDS, 16B per lane. LDS dest = wave-uniform base + lane*16.
__device__ __forceinline__ void gload_lds16(const bf16* g, bf16* l) {
    __builtin_amdgcn_global_load_lds(
        (const __attribute__((address_space(1))) void*)g,
        (__attribute__((address_space(3))) void*)l, 16, 0, 0);
}

#define BAR()   __builtin_amdgcn_s_barrier()
#define LGKM(N) asm volatile("s_waitcnt lgkmcnt(" #N ")" ::: "memory")
#define VMC(N)  asm volatile("s_waitcnt vmcnt(" #N ")" ::: "memory")

// ============================================================================
// Unified min-sync GEMM (r12/r13 schedule, verified). C = A*B^T + bias.
// Tile 128(M) x 64*NF(N), BK=64, 2-buf. 512 thr = 8 waves (2Mx4N), wave out
// 64 x 16*NF = acc[4][NF]. NF=6: GEMM1 (grid 512 = 2.0 CU rounds, 128KB LDS).
// NF=4: GEMM2 (grid 256 = 1.0 round, 96KB LDS).
// Swizzle (verified r7-r13, 0 conflicts): read byte ^= (row&7)<<4; inverse on
// GLOBAL k (kel = ((lane&7)^(lane>>3))*8); linear gload_lds dest.
// Per-tile: { 2*(4+NF) ds_reads (kk0 first); stage(t+1) 2+NF gloads;
//   LGKM(4+NF) MFMA kk0; LGKM(0) MFMA kk1; VMC(0) [t+1 issued a full tile
//   ago => ~free]; BAR }
// Hazard: stage(t+1) writes buf^1 whose tile-(t-1) reads all retired before
// BAR(t-1) (LGKM(0) precedes final MFMA) -> BAR orders write-after-read.
// ============================================================================
template <int NF, typename CT>
__global__ __launch_bounds__(512, 2)
void gemm_u(const bf16* __restrict__ A, const bf16* __restrict__ B,
            const float* __restrict__ bias, CT* __restrict__ C,
            int M, int N, int K, int gx) {
    __shared__ alignas(1024) bf16 smem[2][(128 + 64 * NF) * 64];

    const int t    = threadIdx.x;
    const int lane = t & 63;
    const int wid  = t >> 6;
    const int wr   = wid >> 2;   // 0..1
    const int wc   = wid & 3;    // 0..3

    const int nwg = gridDim.x;
    const int bid = blockIdx.x;
    const int wg  = (bid & 7) * (nwg >> 3) + (bid >> 3);
    const int m0  = (wg / gx) * 128;
    const int n0  = (wg % gx) * (64 * NF);
    const int nt  = K / 64;

    const int srow = lane >> 3;
    const int kel  = ((lane & 7) ^ (lane >> 3)) * 8;

    auto stageA = [&](int tt) {            // 16 rows/wave = 2 gloads
        if (tt >= nt) return;
        bf16* lp = &smem[tt & 1][wid * 1024];
        const bf16* gp = A + (size_t)(m0 + wid * 16 + srow) * K + tt * 64 + kel;
        gload_lds16(gp, lp);
        gload_lds16(gp + (size_t)8 * K, lp + 512);
    };
    auto stageB = [&](int tt) {            // 8*NF rows/wave = NF gloads
        if (tt >= nt) return;
        bf16* lp = &smem[tt & 1][8192 + wid * (NF * 512)];
        const bf16* gp = B + (size_t)(n0 + wid * 8 * NF + srow) * K + tt * 64 + kel;
#pragma unroll
        for (int i = 0; i < NF; ++i)
            gload_lds16(gp + (size_t)(i * 8) * K, lp + i * 512);
    };

    const int arow_base = wr * 64 + (lane & 15);
    const int brow_base = wc * (16 * NF) + (lane & 15);
    const int kqb       = (lane >> 4) * 16;
    auto LDA = [&](int buf, int kk, int m) -> bf16x8 {
        const int row = arow_base + m * 16;
        const int ab  = row * 128 + ((kk * 64 + kqb) ^ ((row & 7) << 4));
        return *(const bf16x8*)((const char*)&smem[buf][0] + ab);
    };
    auto LDB = [&](int buf, int kk, int n) -> bf16x8 {
        const int row = brow_base + n * 16;
        const int bb  = 16384 + row * 128 + ((kk * 64 + kqb) ^ ((row & 7) << 4));
        return *(const bf16x8*)((const char*)&smem[buf][0] + bb);
    };

    f32x4 acc[4][NF] = {};
    bf16x8 af0[4], bv0[NF], af1[4], bv1[NF];

    // prologue
    stageA(0); stageB(0);
    VMC(0);
    BAR();

    for (int tt = 0; tt < nt; ++tt) {
        const int buf = tt & 1;

        // frag reads first: kk0 (oldest 4+NF), then kk1
#pragma unroll
        for (int m = 0; m < 4; ++m) af0[m] = LDA(buf, 0, m);
#pragma unroll
        for (int n = 0; n < NF; ++n) bv0[n] = LDB(buf, 0, n);
#pragma unroll
        for (int m = 0; m < 4; ++m) af1[m] = LDA(buf, 1, m);
#pragma unroll
        for (int n = 0; n < NF; ++n) bv1[n] = LDB(buf, 1, n);

        // stage t+1 (lands during this tile's compute)
        stageA(tt + 1); stageB(tt + 1);

        if constexpr (NF == 6) { LGKM(10); } else { LGKM(8); }
        __builtin_amdgcn_s_setprio(1);
#pragma unroll
        for (int m = 0; m < 4; ++m)
#pragma unroll
            for (int n = 0; n < NF; ++n)
                acc[m][n] = __builtin_amdgcn_mfma_f32_16x16x32_bf16(
                    af0[m], bv0[n], acc[m][n], 0, 0, 0);
        __builtin_amdgcn_s_setprio(0);
        LGKM(0);
        __builtin_amdgcn_s_setprio(1);
#pragma unroll
        for (int m = 0; m < 4; ++m)
#pragma unroll
            for (int n = 0; n < NF; ++n)
                acc[m][n] = __builtin_amdgcn_mfma_f32_16x16x32_bf16(
                    af1[m], bv1[n], acc[m][n], 0, 0, 0);
        __builtin_amdgcn_s_setprio(0);

        VMC(0);                          // t+1 landed (issued a full tile ago)
        BAR();
    }

    // epilogue
#pragma unroll
    for (int m = 0; m < 4; ++m) {
        const int row = m0 + wr * 64 + m * 16 + (lane >> 4) * 4;
#pragma unroll
        for (int n = 0; n < NF; ++n) {
            const int col = n0 + wc * (16 * NF) + n * 16 + (lane & 15);
            const float bval = bias[col];
#pragma unroll
            for (int r = 0; r < 4; ++r)
                store1(&C[(size_t)(row + r) * N + col], acc[m][n][r] + bval);
        }
    }
}

// ---- fused fp32 -> bf16 conversion of THREE buffers, 4 elems/thread ----
__global__ __launch_bounds__(256)
void cvt3_f32_bf16(const float* __restrict__ in1, bf16* __restrict__ out1, int n1,
                   const float* __restrict__ in2, bf16* __restrict__ out2, int n2,
                   const float* __restrict__ in3, bf16* __restrict__ out3, int n3) {
    int i = blockIdx.x * 256 + threadIdx.x;
    const float* in;
    bf16* out;
    if (i < n1)           { in = in1; out = out1; }
    else if (i < n1 + n2) { in = in2; out = out2; i -= n1; }
    else                  { in = in3; out = out3; i -= n1 + n2; if (i >= n3) return; }
    float4 v = ((const float4*)in)[i];
    ushort4 o = {f2b(v.x), f2b(v.y), f2b(v.z), f2b(v.w)};
    ((ushort4*)out)[i] = o;
}

// ---- fused fp32 -> bf16 conversion of TWO buffers, 4 elems/thread ----
__global__ __launch_bounds__(256)
void cvt2_f32_bf16(const float* __restrict__ in1, bf16* __restrict__ out1, int n1,
                   const float* __restrict__ in2, bf16* __restrict__ out2, int n2) {
    int i = blockIdx.x * 256 + threadIdx.x;
    const float* in;
    bf16* out;
    if (i < n1) { in = in1; out = out1; }
    else        { in = in2; out = out2; i -= n1; if (i >= n2) return; }
    float4 v = ((const float4*)in)[i];
    ushort4 o = {f2b(v.x), f2b(v.y), f2b(v.z), f2b(v.w)};
    ((ushort4*)out)[i] = o;
}

// ---- fp32 -> bf16 conversion, 4 elems/thread ----
__global__ __launch_bounds__(256)
void cvt_f32_bf16(const float* __restrict__ in, bf16* __restrict__ out, int n4) {
    int i = blockIdx.x * 256 + threadIdx.x;
    if (i >= n4) return;
    float4 v = ((const float4*)in)[i];
    ushort4 o = {f2b(v.x), f2b(v.y), f2b(v.z), f2b(v.w)};
    ((ushort4*)out)[i] = o;
}

// ---- Per-token attention over heads axis + scrambled T write ----
__global__ __launch_bounds__(256)
void attn_kernel(const bf16* __restrict__ qkv, bf16* __restrict__ T) {
    __shared__ float lds[4][48 * 68];

    const int wave = threadIdx.x >> 6;
    const int lane = threadIdx.x & 63;
    const int token = blockIdx.x * 4 + wave;
    const int n = token >> 11;
    const int s = token & 2047;

    float* L = lds[wave];
    const bf16* src = qkv + (size_t)token * 3072;

#pragma unroll
    for (int i = 0; i < 6; ++i) {
        int idx = i * 64 + lane;
        uint4 v = *reinterpret_cast<const uint4*>(src + (size_t)idx * 8);
        int e0 = idx * 8;
        float* dst = &L[(e0 >> 6) * 68 + (e0 & 63)];
        float4 a, b;
        a.x = b2f((unsigned short)(v.x & 0xffff));
        a.y = b2f((unsigned short)(v.x >> 16));
        a.z = b2f((unsigned short)(v.y & 0xffff));
        a.w = b2f((unsigned short)(v.y >> 16));
        b.x = b2f((unsigned short)(v.z & 0xffff));
        b.y = b2f((unsigned short)(v.z >> 16));
        b.z = b2f((unsigned short)(v.w & 0xffff));
        b.w = b2f((unsigned short)(v.w >> 16));
        *(float4*)dst = a;
        *(float4*)(dst + 4) = b;
    }
    __syncthreads();

    const int q0 = lane & 15;
    const int g  = lane >> 4;

    float e[4] = {0.f, 0.f, 0.f, 0.f};
    const float* Qr = &L[q0 * 68];
    const float* K0 = &L[(16 + g * 4) * 68];
#pragma unroll
    for (int d = 0; d < 64; d += 4) {
        float4 q4 = *(const float4*)(Qr + d);
#pragma unroll
        for (int j = 0; j < 4; ++j) {
            float4 k4 = *(const float4*)(K0 + j * 68 + d);
            e[j] += q4.x * k4.x + q4.y * k4.y + q4.z * k4.z + q4.w * k4.w;
        }
    }
#pragma unroll
    for (int j = 0; j < 4; ++j) e[j] *= 0.125f;

    float m = fmaxf(fmaxf(e[0], e[1]), fmaxf(e[2], e[3]));
    m = fmaxf(m, __shfl_xor(m, 16));
    m = fmaxf(m, __shfl_xor(m, 32));
    float p[4], sum = 0.f;
#pragma unroll
    for (int j = 0; j < 4; ++j) { p[j] = __expf(e[j] - m); sum += p[j]; }
    sum += __shfl_xor(sum, 16);
    sum += __shfl_xor(sum, 32);
    const float inv = 1.0f / sum;

    float prow[16];
#pragma unroll
    for (int j = 0; j < 4; ++j) {
        prow[g * 4 + j]         = p[j] * inv;
        prow[((g ^ 1) * 4) + j] = __shfl_xor(p[j], 16) * inv;
        prow[((g ^ 2) * 4) + j] = __shfl_xor(p[j], 32) * inv;
        prow[((g ^ 3) * 4) + j] = __shfl_xor(p[j], 48) * inv;
    }

    const int d0 = g * 16;
    float4 o4[4] = {};
#pragma unroll
    for (int k = 0; k < 16; ++k) {
        const float p1 = prow[k];
        const float* Vr = &L[(32 + k) * 68 + d0];
#pragma unroll
        for (int c = 0; c < 4; ++c) {
            float4 v = *(const float4*)(Vr + c * 4);
            o4[c].x += p1 * v.x; o4[c].y += p1 * v.y;
            o4[c].z += p1 * v.z; o4[c].w += p1 * v.w;
        }
    }
    unsigned short outv[16];
#pragma unroll
    for (int c = 0; c < 4; ++c) {
        outv[c * 4 + 0] = f2b(o4[c].x); outv[c * 4 + 1] = f2b(o4[c].y);
        outv[c * 4 + 2] = f2b(o4[c].z); outv[c * 4 + 3] = f2b(o4[c].w);
    }
    const int sp = q0 * 128 + (s >> 4);
    size_t off = ((size_t)n * 2048 + sp) * 1024 + (size_t)(s & 15) * 64 + d0;
    uint4* dst = reinterpret_cast<uint4*>(T + off);
    const uint4* sv = reinterpret_cast<const uint4*>(outv);
    dst[0] = sv[0];
    dst[1] = sv[1];
}

extern "C" void kernel_launch(void* const* d_in, const int* in_sizes, int n_in,
                              void* d_out, int out_size, void* d_ws, size_t ws_size,
                              hipStream_t stream) {
    const float* x     = (const float*)d_in[0];   // (4,2048,1024)
    const float* w_qkv = (const float*)d_in[1];   // (3072,1024)
    const float* b_qkv = (const float*)d_in[2];   // (3072,)
    const float* w_out = (const float*)d_in[3];   // (1024,1024)
    const float* b_out = (const float*)d_in[4];   // (1024,)
    float* out = (float*)d_out;                   // (4,2048,1024) fp32

    const int M = 8192, E = 3072, K = 1024, D = 1024;

    // ws: [0, 48MiB) qkv bf16; [48MiB, 64MiB) T bf16  (= exactly 64 MiB).
    // Optional: [64MiB, 66MiB) W2e (w_out bf16) if ws_size permits.
    // d_out doubles as scratch until GEMM2 rewrites it: W1b then X16.
    bf16* qkv = (bf16*)d_ws;
    bf16* T   = qkv + (size_t)M * E;
    bf16* W1b = (bf16*)d_out;
    bf16* X16 = W1b + (size_t)E * K;

    dim3 blk(256);
    const int n1 = M * K / 4, n2 = E * K / 4, n3 = D * K / 4;
    const size_t base = (size_t)64 * 1024 * 1024;
    const size_t need = base + (size_t)D * K * sizeof(bf16);

    if (ws_size >= need) {
        // 4-dispatch path: all converts fused; w_out bf16 lives past 64MiB.
        bf16* W2e = (bf16*)((char*)d_ws + base);
        cvt3_f32_bf16<<<dim3((n1 + n2 + n3 + 255) / 256), blk, 0, stream>>>(
            x, X16, n1, w_qkv, W1b, n2, w_out, W2e, n3);
        gemm_u<6, bf16><<<dim3((M / 128) * (E / 384)), dim3(512), 0, stream>>>(
            X16, W1b, b_qkv, qkv, M, E, K, E / 384);
        attn_kernel<<<dim3(M / 4), blk, 0, stream>>>(qkv, T);
        gemm_u<4, float><<<dim3((M / 128) * (D / 256)), dim3(512), 0, stream>>>(
            T, W2e, b_out, out, M, D, K, D / 256);
    } else {
        // 5-dispatch fallback (r13, verified): W2b reuses dead qkv region.
        bf16* W2b = qkv;
        cvt2_f32_bf16<<<dim3((n1 + n2) / 256), blk, 0, stream>>>(
            x, X16, n1, w_qkv, W1b, n2);
        gemm_u<6, bf16><<<dim3((M / 128) * (E / 384)), dim3(512), 0, stream>>>(
            X16, W1b, b_qkv, qkv, M, E, K, E / 384);
        attn_kernel<<<dim3(M / 4), blk, 0, stream>>>(qkv, T);
        cvt_f32_bf16<<<dim3(n3 / 256), blk, 0, stream>>>(w_out, W2b, n3);
        gemm_u<4, float><<<dim3((M / 128) * (D / 256)), dim3(512), 0, stream>>>(
            T, W2b, b_out, out, M, D, K, D / 256);
    }
}

// Round 15
// 108.536 us; speedup vs baseline: 1.3644x; 1.0591x over previous
//
#include <hip/hip_runtime.h>
#include <hip/hip_bf16.h>

// N=4, S=2048, D_MODEL=1024, HEADS=16, HEAD_DIM=64. M = 8192 tokens, E = 3072.

typedef __hip_bfloat16 bf16;
using bf16x8 = __attribute__((ext_vector_type(8))) short;
using f32x4  = __attribute__((ext_vector_type(4))) float;

__device__ __forceinline__ float b2f(unsigned short u) {
    return __uint_as_float(((unsigned)u) << 16);
}
__device__ __forceinline__ unsigned short f2b(float f) {
    bf16 h = __float2bfloat16(f);
    return *reinterpret_cast<unsigned short*>(&h);
}
__device__ __forceinline__ void store1(float* p, float v) { *p = v; }
__device__ __forceinline__ void store1(bf16* p, float v) { *p = __float2bfloat16(v); }

// async global->LDS, 16B per lane. LDS dest = wave-uniform base + lane*16.
__device__ __forceinline__ void gload_lds16(const bf16* g, bf16* l) {
    __builtin_amdgcn_global_load_lds(
        (const __attribute__((address_space(1))) void*)g,
        (__attribute__((address_space(3))) void*)l, 16, 0, 0);
}

#define BAR()   __builtin_amdgcn_s_barrier()
#define LGKM(N) asm volatile("s_waitcnt lgkmcnt(" #N ")" ::: "memory")
#define VMC(N)  asm volatile("s_waitcnt vmcnt(" #N ")" ::: "memory")

// ============================================================================
// Unified min-sync GEMM (r12/r13 schedule, verified). C = A*B^T + bias.
// Tile 128(M) x 64*NF(N), BK=64, 2-buf. 512 thr = 8 waves (2Mx4N), wave out
// 64 x 16*NF = acc[4][NF].
//   NF=3, MINW=4: GEMM1 — 80KB LDS -> 2 blocks/CU (inter-block port/MFMA
//     overlap, m114/m97 mechanism); grid 1024 = 2.0 rounds of 2-resident.
//   NF=4, MINW=2: GEMM2 — 96KB LDS, grid 256 = 1.0 round.
// Swizzle (verified r7-r14, 0 conflicts): read byte ^= (row&7)<<4; inverse on
// GLOBAL k (kel = ((lane&7)^(lane>>3))*8); linear gload_lds dest.
// Per-tile: { 2*(4+NF) ds_reads (kk0 first); stage(t+1) 2+NF gloads;
//   LGKM(4+NF) MFMA kk0; LGKM(0) MFMA kk1; VMC(0) [t+1 issued a full tile
//   ago => ~free]; BAR }
// Hazard: stage(t+1) writes buf^1 whose tile-(t-1) reads all retired before
// BAR(t-1) (LGKM(0) precedes final MFMA) -> BAR orders write-after-read.
// ============================================================================
template <int NF, typename CT, int MINW = 2>
__global__ __launch_bounds__(512, MINW)
void gemm_u(const bf16* __restrict__ A, const bf16* __restrict__ B,
            const float* __restrict__ bias, CT* __restrict__ C,
            int M, int N, int K, int gx) {
    __shared__ alignas(1024) bf16 smem[2][(128 + 64 * NF) * 64];

    const int t    = threadIdx.x;
    const int lane = t & 63;
    const int wid  = t >> 6;
    const int wr   = wid >> 2;   // 0..1
    const int wc   = wid & 3;    // 0..3

    const int nwg = gridDim.x;
    const int bid = blockIdx.x;
    const int wg  = (bid & 7) * (nwg >> 3) + (bid >> 3);
    const int m0  = (wg / gx) * 128;
    const int n0  = (wg % gx) * (64 * NF);
    const int nt  = K / 64;

    const int srow = lane >> 3;
    const int kel  = ((lane & 7) ^ (lane >> 3)) * 8;

    auto stageA = [&](int tt) {            // 16 rows/wave = 2 gloads
        if (tt >= nt) return;
        bf16* lp = &smem[tt & 1][wid * 1024];
        const bf16* gp = A + (size_t)(m0 + wid * 16 + srow) * K + tt * 64 + kel;
        gload_lds16(gp, lp);
        gload_lds16(gp + (size_t)8 * K, lp + 512);
    };
    auto stageB = [&](int tt) {            // 8*NF rows/wave = NF gloads
        if (tt >= nt) return;
        bf16* lp = &smem[tt & 1][8192 + wid * (NF * 512)];
        const bf16* gp = B + (size_t)(n0 + wid * 8 * NF + srow) * K + tt * 64 + kel;
#pragma unroll
        for (int i = 0; i < NF; ++i)
            gload_lds16(gp + (size_t)(i * 8) * K, lp + i * 512);
    };

    const int arow_base = wr * 64 + (lane & 15);
    const int brow_base = wc * (16 * NF) + (lane & 15);
    const int kqb       = (lane >> 4) * 16;
    auto LDA = [&](int buf, int kk, int m) -> bf16x8 {
        const int row = arow_base + m * 16;
        const int ab  = row * 128 + ((kk * 64 + kqb) ^ ((row & 7) << 4));
        return *(const bf16x8*)((const char*)&smem[buf][0] + ab);
    };
    auto LDB = [&](int buf, int kk, int n) -> bf16x8 {
        const int row = brow_base + n * 16;
        const int bb  = 16384 + row * 128 + ((kk * 64 + kqb) ^ ((row & 7) << 4));
        return *(const bf16x8*)((const char*)&smem[buf][0] + bb);
    };

    f32x4 acc[4][NF] = {};
    bf16x8 af0[4], bv0[NF], af1[4], bv1[NF];

    // prologue
    stageA(0); stageB(0);
    VMC(0);
    BAR();

    for (int tt = 0; tt < nt; ++tt) {
        const int buf = tt & 1;

        // frag reads first: kk0 (oldest 4+NF), then kk1
#pragma unroll
        for (int m = 0; m < 4; ++m) af0[m] = LDA(buf, 0, m);
#pragma unroll
        for (int n = 0; n < NF; ++n) bv0[n] = LDB(buf, 0, n);
#pragma unroll
        for (int m = 0; m < 4; ++m) af1[m] = LDA(buf, 1, m);
#pragma unroll
        for (int n = 0; n < NF; ++n) bv1[n] = LDB(buf, 1, n);

        // stage t+1 (lands during this tile's compute)
        stageA(tt + 1); stageB(tt + 1);

        if constexpr (NF == 6)      { LGKM(10); }
        else if constexpr (NF == 4) { LGKM(8); }
        else                        { LGKM(7); }   // NF == 3
        __builtin_amdgcn_s_setprio(1);
#pragma unroll
        for (int m = 0; m < 4; ++m)
#pragma unroll
            for (int n = 0; n < NF; ++n)
                acc[m][n] = __builtin_amdgcn_mfma_f32_16x16x32_bf16(
                    af0[m], bv0[n], acc[m][n], 0, 0, 0);
        __builtin_amdgcn_s_setprio(0);
        LGKM(0);
        __builtin_amdgcn_s_setprio(1);
#pragma unroll
        for (int m = 0; m < 4; ++m)
#pragma unroll
            for (int n = 0; n < NF; ++n)
                acc[m][n] = __builtin_amdgcn_mfma_f32_16x16x32_bf16(
                    af1[m], bv1[n], acc[m][n], 0, 0, 0);
        __builtin_amdgcn_s_setprio(0);

        VMC(0);                          // t+1 landed (issued a full tile ago)
        BAR();
    }

    // epilogue
#pragma unroll
    for (int m = 0; m < 4; ++m) {
        const int row = m0 + wr * 64 + m * 16 + (lane >> 4) * 4;
#pragma unroll
        for (int n = 0; n < NF; ++n) {
            const int col = n0 + wc * (16 * NF) + n * 16 + (lane & 15);
            const float bval = bias[col];
#pragma unroll
            for (int r = 0; r < 4; ++r)
                store1(&C[(size_t)(row + r) * N + col], acc[m][n][r] + bval);
        }
    }
}

// ---- fused fp32 -> bf16 conversion of THREE buffers, 4 elems/thread ----
__global__ __launch_bounds__(256)
void cvt3_f32_bf16(const float* __restrict__ in1, bf16* __restrict__ out1, int n1,
                   const float* __restrict__ in2, bf16* __restrict__ out2, int n2,
                   const float* __restrict__ in3, bf16* __restrict__ out3, int n3) {
    int i = blockIdx.x * 256 + threadIdx.x;
    const float* in;
    bf16* out;
    if (i < n1)           { in = in1; out = out1; }
    else if (i < n1 + n2) { in = in2; out = out2; i -= n1; }
    else                  { in = in3; out = out3; i -= n1 + n2; if (i >= n3) return; }
    float4 v = ((const float4*)in)[i];
    ushort4 o = {f2b(v.x), f2b(v.y), f2b(v.z), f2b(v.w)};
    ((ushort4*)out)[i] = o;
}

// ---- fused fp32 -> bf16 conversion of TWO buffers, 4 elems/thread ----
__global__ __launch_bounds__(256)
void cvt2_f32_bf16(const float* __restrict__ in1, bf16* __restrict__ out1, int n1,
                   const float* __restrict__ in2, bf16* __restrict__ out2, int n2) {
    int i = blockIdx.x * 256 + threadIdx.x;
    const float* in;
    bf16* out;
    if (i < n1) { in = in1; out = out1; }
    else        { in = in2; out = out2; i -= n1; if (i >= n2) return; }
    float4 v = ((const float4*)in)[i];
    ushort4 o = {f2b(v.x), f2b(v.y), f2b(v.z), f2b(v.w)};
    ((ushort4*)out)[i] = o;
}

// ---- fp32 -> bf16 conversion, 4 elems/thread ----
__global__ __launch_bounds__(256)
void cvt_f32_bf16(const float* __restrict__ in, bf16* __restrict__ out, int n4) {
    int i = blockIdx.x * 256 + threadIdx.x;
    if (i >= n4) return;
    float4 v = ((const float4*)in)[i];
    ushort4 o = {f2b(v.x), f2b(v.y), f2b(v.z), f2b(v.w)};
    ((ushort4*)out)[i] = o;
}

// ---- Per-token attention over heads axis + scrambled T write ----
__global__ __launch_bounds__(256)
void attn_kernel(const bf16* __restrict__ qkv, bf16* __restrict__ T) {
    __shared__ float lds[4][48 * 68];

    const int wave = threadIdx.x >> 6;
    const int lane = threadIdx.x & 63;
    const int token = blockIdx.x * 4 + wave;
    const int n = token >> 11;
    const int s = token & 2047;

    float* L = lds[wave];
    const bf16* src = qkv + (size_t)token * 3072;

#pragma unroll
    for (int i = 0; i < 6; ++i) {
        int idx = i * 64 + lane;
        uint4 v = *reinterpret_cast<const uint4*>(src + (size_t)idx * 8);
        int e0 = idx * 8;
        float* dst = &L[(e0 >> 6) * 68 + (e0 & 63)];
        float4 a, b;
        a.x = b2f((unsigned short)(v.x & 0xffff));
        a.y = b2f((unsigned short)(v.x >> 16));
        a.z = b2f((unsigned short)(v.y & 0xffff));
        a.w = b2f((unsigned short)(v.y >> 16));
        b.x = b2f((unsigned short)(v.z & 0xffff));
        b.y = b2f((unsigned short)(v.z >> 16));
        b.z = b2f((unsigned short)(v.w & 0xffff));
        b.w = b2f((unsigned short)(v.w >> 16));
        *(float4*)dst = a;
        *(float4*)(dst + 4) = b;
    }
    __syncthreads();

    const int q0 = lane & 15;
    const int g  = lane >> 4;

    float e[4] = {0.f, 0.f, 0.f, 0.f};
    const float* Qr = &L[q0 * 68];
    const float* K0 = &L[(16 + g * 4) * 68];
#pragma unroll
    for (int d = 0; d < 64; d += 4) {
        float4 q4 = *(const float4*)(Qr + d);
#pragma unroll
        for (int j = 0; j < 4; ++j) {
            float4 k4 = *(const float4*)(K0 + j * 68 + d);
            e[j] += q4.x * k4.x + q4.y * k4.y + q4.z * k4.z + q4.w * k4.w;
        }
    }
#pragma unroll
    for (int j = 0; j < 4; ++j) e[j] *= 0.125f;

    float m = fmaxf(fmaxf(e[0], e[1]), fmaxf(e[2], e[3]));
    m = fmaxf(m, __shfl_xor(m, 16));
    m = fmaxf(m, __shfl_xor(m, 32));
    float p[4], sum = 0.f;
#pragma unroll
    for (int j = 0; j < 4; ++j) { p[j] = __expf(e[j] - m); sum += p[j]; }
    sum += __shfl_xor(sum, 16);
    sum += __shfl_xor(sum, 32);
    const float inv = 1.0f / sum;

    float prow[16];
#pragma unroll
    for (int j = 0; j < 4; ++j) {
        prow[g * 4 + j]         = p[j] * inv;
        prow[((g ^ 1) * 4) + j] = __shfl_xor(p[j], 16) * inv;
        prow[((g ^ 2) * 4) + j] = __shfl_xor(p[j], 32) * inv;
        prow[((g ^ 3) * 4) + j] = __shfl_xor(p[j], 48) * inv;
    }

    const int d0 = g * 16;
    float4 o4[4] = {};
#pragma unroll
    for (int k = 0; k < 16; ++k) {
        const float p1 = prow[k];
        const float* Vr = &L[(32 + k) * 68 + d0];
#pragma unroll
        for (int c = 0; c < 4; ++c) {
            float4 v = *(const float4*)(Vr + c * 4);
            o4[c].x += p1 * v.x; o4[c].y += p1 * v.y;
            o4[c].z += p1 * v.z; o4[c].w += p1 * v.w;
        }
    }
    unsigned short outv[16];
#pragma unroll
    for (int c = 0; c < 4; ++c) {
        outv[c * 4 + 0] = f2b(o4[c].x); outv[c * 4 + 1] = f2b(o4[c].y);
        outv[c * 4 + 2] = f2b(o4[c].z); outv[c * 4 + 3] = f2b(o4[c].w);
    }
    const int sp = q0 * 128 + (s >> 4);
    size_t off = ((size_t)n * 2048 + sp) * 1024 + (size_t)(s & 15) * 64 + d0;
    uint4* dst = reinterpret_cast<uint4*>(T + off);
    const uint4* sv = reinterpret_cast<const uint4*>(outv);
    dst[0] = sv[0];
    dst[1] = sv[1];
}

extern "C" void kernel_launch(void* const* d_in, const int* in_sizes, int n_in,
                              void* d_out, int out_size, void* d_ws, size_t ws_size,
                              hipStream_t stream) {
    const float* x     = (const float*)d_in[0];   // (4,2048,1024)
    const float* w_qkv = (const float*)d_in[1];   // (3072,1024)
    const float* b_qkv = (const float*)d_in[2];   // (3072,)
    const float* w_out = (const float*)d_in[3];   // (1024,1024)
    const float* b_out = (const float*)d_in[4];   // (1024,)
    float* out = (float*)d_out;                   // (4,2048,1024) fp32

    const int M = 8192, E = 3072, K = 1024, D = 1024;

    // ws: [0, 48MiB) qkv bf16; [48MiB, 64MiB) T bf16  (= exactly 64 MiB).
    // Optional: [64MiB, 66MiB) W2e (w_out bf16) if ws_size permits.
    // d_out doubles as scratch until GEMM2 rewrites it: W1b then X16.
    bf16* qkv = (bf16*)d_ws;
    bf16* T   = qkv + (size_t)M * E;
    bf16* W1b = (bf16*)d_out;
    bf16* X16 = W1b + (size_t)E * K;

    dim3 blk(256);
    const int n1 = M * K / 4, n2 = E * K / 4, n3 = D * K / 4;
    const size_t base = (size_t)64 * 1024 * 1024;
    const size_t need = base + (size_t)D * K * sizeof(bf16);

    if (ws_size >= need) {
        // 4-dispatch path: all converts fused; w_out bf16 lives past 64MiB.
        bf16* W2e = (bf16*)((char*)d_ws + base);
        cvt3_f32_bf16<<<dim3((n1 + n2 + n3 + 255) / 256), blk, 0, stream>>>(
            x, X16, n1, w_qkv, W1b, n2, w_out, W2e, n3);
        // GEMM1: 128x192 tiles, 2 blocks/CU, grid 1024 = 2.0 rounds 2-resident
        gemm_u<3, bf16, 4><<<dim3((M / 128) * (E / 192)), dim3(512), 0, stream>>>(
            X16, W1b, b_qkv, qkv, M, E, K, E / 192);
        attn_kernel<<<dim3(M / 4), blk, 0, stream>>>(qkv, T);
        gemm_u<4, float, 2><<<dim3((M / 128) * (D / 256)), dim3(512), 0, stream>>>(
            T, W2e, b_out, out, M, D, K, D / 256);
    } else {
        // 5-dispatch fallback: W2b reuses dead qkv region.
        bf16* W2b = qkv;
        cvt2_f32_bf16<<<dim3((n1 + n2) / 256), blk, 0, stream>>>(
            x, X16, n1, w_qkv, W1b, n2);
        gemm_u<3, bf16, 4><<<dim3((M / 128) * (E / 192)), dim3(512), 0, stream>>>(
            X16, W1b, b_qkv, qkv, M, E, K, E / 192);
        attn_kernel<<<dim3(M / 4), blk, 0, stream>>>(qkv, T);
        cvt_f32_bf16<<<dim3(n3 / 256), blk, 0, stream>>>(w_out, W2b, n3);
        gemm_u<4, float, 2><<<dim3((M / 128) * (D / 256)), dim3(512), 0, stream>>>(
            T, W2b, b_out, out, M, D, K, D / 256);
    }
}